// Round 9
// baseline (1700.538 us; speedup 1.0000x reference)
//
#include <hip/hip_runtime.h>
#include <stdint.h>
#include <stddef.h>

// ---------------------------------------------------------------------------
// Controller (LSTM policy sampler) — round 8 (perf; r6/r7 PASSED absmax 0.0).
// R7 post-mortem: launch_bounds(448,4) forced VGPR=64 -> scratch spills
// (530 MB HBM traffic/dispatch). Fix: rows/thread 8->4 (acc file halved),
// ROWS=16/block, 2560 blocks, launch_bounds(448,6) -> ~85 VGPR, 3 blocks/CU
// (21 waves). hbuf padded [HID][18] kills the h-write bank collision.
// ---------------------------------------------------------------------------

#define NOPS 14
#define NMAGS 10
#define QC 5
#define NSTEP 8
#define TOT 40
#define EMB 32
#define HID 100
#define BTOT 8192
#define ROWS 16
#define RPT 4
#define NT 448
#define NCOL 112
#define NBLK (QC * (BTOT / ROWS))          // 2560
#define HPAD 18

// ws layout (doubles)
#define WHH_D  0
#define WHH_ND (HID * NCOL * 4)            // 44800
#define PX_D   WHH_ND
#define PX_ND  (25 * NCOL * 4)             // 11200
#define LPP_D  (PX_D + PX_ND)              // 56000
#define ENP_D  (LPP_D + QC * BTOT)         // 96960
#define GACC_D (ENP_D + QC * BTOT)         // 137920

// d_out layout (f32)
#define OUT_OPM  (BTOT * TOT)              // 327680
#define OUT_MAGM (OUT_OPM + NOPS)          // 327694
#define OUT_LPS  (OUT_MAGM + NMAGS)        // 327704
#define OUT_ENTS (OUT_LPS + BTOT)          // 335896

struct KeyArr { uint32_t k[TOT * 2]; };

// ---- threefry2x32-20 (jax._src.prng) --------------------------------------
__host__ __device__ inline void tf2x32(uint32_t k0, uint32_t k1,
                                       uint32_t x0, uint32_t x1,
                                       uint32_t& o0, uint32_t& o1) {
  uint32_t k2 = k0 ^ k1 ^ 0x1BD11BDAu;
#define TFR(r) { x0 += x1; x1 = (x1 << (r)) | (x1 >> (32 - (r))); x1 ^= x0; }
  x0 += k0; x1 += k1;
  TFR(13) TFR(15) TFR(26) TFR(6)
  x0 += k1; x1 += k2 + 1u;
  TFR(17) TFR(29) TFR(16) TFR(24)
  x0 += k2; x1 += k0 + 2u;
  TFR(13) TFR(15) TFR(26) TFR(6)
  x0 += k0; x1 += k1 + 3u;
  TFR(17) TFR(29) TFR(16) TFR(24)
  x0 += k1; x1 += k2 + 4u;
  TFR(13) TFR(15) TFR(26) TFR(6)
  x0 += k2; x1 += k0 + 5u;
#undef TFR
  o0 = x0; o1 = x1;
}

// ---- fast f64 exp (|x| <= ~60; rel err ~1e-16) ----------------------------
__device__ __forceinline__ double exp64(double x) {
  double t = x * 1.4426950408889634074;
  double n = rint(t);
  double r = fma(-n, 6.93147180369123816490e-01, x);
  r = fma(-n, 1.90821492927058770002e-10, r);
  double p = 1.6059043836821613e-10;        // 1/13!
  p = fma(p, r, 2.0876756987868099e-9);
  p = fma(p, r, 2.5052108385441720e-8);
  p = fma(p, r, 2.7557319223985888e-7);
  p = fma(p, r, 2.7557319223985893e-6);
  p = fma(p, r, 2.4801587301587302e-5);
  p = fma(p, r, 1.9841269841269841e-4);
  p = fma(p, r, 1.3888888888888889e-3);
  p = fma(p, r, 8.3333333333333332e-3);
  p = fma(p, r, 4.1666666666666664e-2);
  p = fma(p, r, 1.6666666666666666e-1);
  p = fma(p, r, 0.5);
  p = fma(p, r, 1.0);
  p = fma(p, r, 1.0);
  long long ni = (long long)n;
  double sc = __longlong_as_double((1023LL + ni) << 52);
  return p * sc;
}

// ---- fast f64 log (normal x > 0; abs err ~1e-15) --------------------------
__device__ __forceinline__ double log64(double x) {
  long long b = __double_as_longlong(x);
  long long e = ((b >> 52) & 0x7FF) - 1023;
  double m = __longlong_as_double((b & 0x000FFFFFFFFFFFFFLL) |
                                  0x3FF0000000000000LL);
  if (m > 1.4142135623730951) { m *= 0.5; e += 1; }
  double z = (m - 1.0) / (m + 1.0);
  double z2 = z * z;
  double s = 1.0 / 21.0;
  s = fma(s, z2, 1.0 / 19.0);
  s = fma(s, z2, 1.0 / 17.0);
  s = fma(s, z2, 1.0 / 15.0);
  s = fma(s, z2, 1.0 / 13.0);
  s = fma(s, z2, 1.0 / 11.0);
  s = fma(s, z2, 1.0 / 9.0);
  s = fma(s, z2, 1.0 / 7.0);
  s = fma(s, z2, 1.0 / 5.0);
  s = fma(s, z2, 1.0 / 3.0);
  s = fma(s, z2, 1.0);
  double lm = 2.0 * z * s;
  return fma((double)e, 0.6931471805599453094, lm);
}

__device__ __forceinline__ double tanh64(double x) {
  double t = exp64(2.0 * x);
  return 1.0 - 2.0 / (t + 1.0);
}

// ---- gumbel: partitionable threefry bits -> exact f32 uniform -> f64 ------
__device__ __forceinline__ double gumbel64(uint32_t k0, uint32_t k1,
                                           uint32_t e) {
  uint32_t o0, o1;
  tf2x32(k0, k1, 0u, e, o0, o1);
  uint32_t bits = o0 ^ o1;
  float uf = __uint_as_float((bits >> 9) | 0x3f800000u) - 1.0f;  // exact
  double u = (double)uf;
  if (u == 0.0) u = 1.1754943508222875e-38;
  return -log64(-log64(u));
}

// ---- prep: WHH quads (f64), PX = emb @ W_ih^T quads, zero gacc ------------
__global__ void ctrl_prep(const float* __restrict__ emb,
                          const float* __restrict__ W_ih,
                          const float* __restrict__ W_hh,
                          double* __restrict__ ws) {
  int gid = blockIdx.x * blockDim.x + threadIdx.x;
  if (gid < HID * NCOL) {
    int k = gid / NCOL, j = gid % NCOL;
    double* dst = ws + WHH_D + 4 * gid;
    double v0 = 0, v1 = 0, v2 = 0, v3 = 0;
    if (j < HID) {
      v0 = (double)W_hh[(0 * HID + j) * HID + k];
      v1 = (double)W_hh[(1 * HID + j) * HID + k];
      v2 = (double)W_hh[(2 * HID + j) * HID + k];
      v3 = (double)W_hh[(3 * HID + j) * HID + k];
    }
    dst[0] = v0; dst[1] = v1; dst[2] = v2; dst[3] = v3;
  } else if (gid < HID * NCOL + 25 * NCOL) {
    int t = gid - HID * NCOL;
    int a = t / NCOL, j = t % NCOL;
    double* dst = ws + PX_D + 4 * t;
    double v[4] = {0.0, 0.0, 0.0, 0.0};
    if (j < HID && a < 24) {
#pragma unroll
      for (int g = 0; g < 4; ++g) {
        const float* wr = W_ih + (g * HID + j) * EMB;
        const float* ev = emb + a * EMB;
        double acc = 0.0;
        for (int e = 0; e < EMB; ++e)
          acc = fma((double)wr[e], (double)ev[e], acc);
        v[g] = acc;
      }
    }
    dst[0] = v[0]; dst[1] = v[1]; dst[2] = v[2]; dst[3] = v[3];
  }
  if (gid < NOPS + NMAGS) ws[GACC_D + gid] = 0.0;
}

// ---- head matvec + z + gumbel ---------------------------------------------
template <int K>
__device__ __forceinline__ void head_phase(
    int tid, int base_b, const float* __restrict__ Wh,
    const float* __restrict__ bh, uint32_t key0, uint32_t key1,
    const double (*hb)[HPAD], double (*zb)[16], double (*gb)[16]) {
  if (tid < ROWS * K) {
    int r = tid / K, c = tid - r * K;
    const float* wrow = Wh + c * HID;
    double acc = 0.0;
#pragma unroll 4
    for (int k = 0; k < HID; ++k)
      acc = fma((double)wrow[k], hb[k][r], acc);
    zb[r][c] = 2.5 * tanh64(acc + (double)bh[c]);
    gb[r][c] = gumbel64(key0, key1, (uint32_t)((base_b + r) * K + c));
  }
}

// ---- per-row softmax / entropy / gumbel-argmax ----------------------------
template <int K>
__device__ __forceinline__ void sample_phase(
    int r, int base_b, int sidx, int eoff, double (*zb)[16], double (*gb)[16],
    double (*pb)[16], int* act, float* __restrict__ out, double& lp_run,
    double& en_run) {
  double m = zb[r][0];
#pragma unroll
  for (int k = 1; k < K; ++k) m = fmax(m, zb[r][k]);
  double s = 0.0;
#pragma unroll
  for (int k = 0; k < K; ++k) s += exp64(zb[r][k] - m);
  double ls = log64(s);
  double ent = 0.0, best = 0.0, sel = 0.0;
  int bi = 0;
#pragma unroll
  for (int k = 0; k < K; ++k) {
    double zk = zb[r][k];
    double lp = zk - m - ls;
    double pr = exp64(lp);
    pb[r][k] = pr;
    ent = fma(lp, pr, ent);
    double sc = gb[r][k] + zk;           // argmax(z + gumbel), first-max tie
    if (k == 0 || sc > best) { best = sc; bi = k; sel = lp; }
  }
  out[(size_t)(base_b + r) * TOT + sidx] = (float)bi;
  lp_run += sel;
  en_run += -ent;
  act[r] = bi + eoff;
}

// ---- main -----------------------------------------------------------------
__global__ __launch_bounds__(NT, 6)
void ctrl_main(const float* __restrict__ b_ih, const float* __restrict__ b_hh,
               const float* __restrict__ W_op, const float* __restrict__ b_op,
               const float* __restrict__ W_mag, const float* __restrict__ b_mag,
               const double* __restrict__ ws, double* __restrict__ gacc,
               double* __restrict__ lpp, double* __restrict__ enp,
               float* __restrict__ out, KeyArr keys) {
  __shared__ double hbuf[2][HID][HPAD];       // double-buffered h, padded
  __shared__ double zb[ROWS][16], gb[ROWS][16], pb[ROWS][16];
  __shared__ int act[ROWS];

  const int tid = threadIdx.x;
  const int jq = tid % NCOL;
  const int rb = (tid / NCOL) * RPT;
  const int bid = blockIdx.x;
  const int q = bid >> 9;                     // 5 q x 512 row-groups
  const int base_b = (bid & 511) * ROWS;
  const bool on = (jq < HID);

  for (int t = tid; t < 2 * HID * HPAD; t += NT) (&hbuf[0][0][0])[t] = 0.0;
  if (tid < ROWS) act[tid] = 24;              // step-0 input: zero vector

  const double* WHH = ws + WHH_D;
  const double* PX = ws + PX_D;

  double bsi = 0, bsf = 0, bsg = 0, bso = 0;
  if (on) {
    bsi = (double)b_ih[jq]       + (double)b_hh[jq];
    bsf = (double)b_ih[100 + jq] + (double)b_hh[100 + jq];
    bsg = (double)b_ih[200 + jq] + (double)b_hh[200 + jq];
    bso = (double)b_ih[300 + jq] + (double)b_hh[300 + jq];
  }

  double creg[RPT];
#pragma unroll
  for (int r = 0; r < RPT; ++r) creg[r] = 0.0;
  double lp_run = 0.0, en_run = 0.0, op_run = 0.0, mag_run = 0.0;
  int cur = 0;
  __syncthreads();

  for (int js = 0; js < NSTEP; ++js) {
    const int nxt = cur ^ 1;
    // ---- gates = PX[act] + h @ WHH (4 rows/thread, f64 fma) ----
    double ai[RPT], af[RPT], ag[RPT], ao[RPT];
#pragma unroll
    for (int r = 0; r < RPT; ++r) {
      const double* px = PX + 4 * ((size_t)act[rb + r] * NCOL + jq);
      ai[r] = px[0]; af[r] = px[1]; ag[r] = px[2]; ao[r] = px[3];
    }
#pragma unroll 2
    for (int k = 0; k < HID; ++k) {
      const double* w = WHH + 4 * (k * NCOL + jq);
      double wi = w[0], wf = w[1], wg = w[2], wo = w[3];
      const double* hrow = &hbuf[cur][k][rb];
      double2 h01 = *(const double2*)(hrow + 0);
      double2 h23 = *(const double2*)(hrow + 2);
      double hv[RPT] = {h01.x, h01.y, h23.x, h23.y};
#pragma unroll
      for (int r = 0; r < RPT; ++r) {
        ai[r] = fma(wi, hv[r], ai[r]);
        af[r] = fma(wf, hv[r], af[r]);
        ag[r] = fma(wg, hv[r], ag[r]);
        ao[r] = fma(wo, hv[r], ao[r]);
      }
    }
    if (on) {
      double hw[RPT];
#pragma unroll
      for (int r = 0; r < RPT; ++r) {
        double gi = ai[r] + bsi, gf = af[r] + bsf;
        double gg = ag[r] + bsg, go = ao[r] + bso;
        double ef = exp64(-gf);
        double ei = exp64(-gi);
        double eg = exp64(2.0 * gg);
        double eo = exp64(-go);
        // c2 = sigmoid(f)*c + sigmoid(i)*tanh(g)
        double c2 = creg[r] / (1.0 + ef) +
                    (eg - 1.0) / ((eg + 1.0) * (1.0 + ei));
        creg[r] = c2;
        double ec = exp64(2.0 * c2);
        hw[r] = (ec - 1.0) / ((ec + 1.0) * (1.0 + eo));  // sig(o)*tanh(c2)
      }
      double* dst = &hbuf[nxt][jq][rb];
      ((double2*)dst)[0] = make_double2(hw[0], hw[1]);
      ((double2*)dst)[1] = make_double2(hw[2], hw[3]);
    }
    __syncthreads();                         // bar1: h visible, reads done

    const int sidx = q * NSTEP + js;
    const uint32_t key0 = keys.k[2 * sidx], key1 = keys.k[2 * sidx + 1];
    if (js & 1)
      head_phase<NMAGS>(tid, base_b, W_mag, b_mag, key0, key1, hbuf[nxt], zb, gb);
    else
      head_phase<NOPS>(tid, base_b, W_op, b_op, key0, key1, hbuf[nxt], zb, gb);
    __syncthreads();                         // bar2: zb/gb visible

    if (tid < ROWS) {
      if (js & 1)
        sample_phase<NMAGS>(tid, base_b, sidx, NOPS, zb, gb, pb, act, out,
                            lp_run, en_run);
      else
        sample_phase<NOPS>(tid, base_b, sidx, 0, zb, gb, pb, act, out,
                           lp_run, en_run);
    }
    __syncthreads();                         // bar3: pb/act visible

    if (js & 1) {
      if (tid < NMAGS) {
        double cs = 0.0;
        for (int r = 0; r < ROWS; ++r) cs += pb[r][tid];
        mag_run += cs;
      }
    } else {
      if (tid < NOPS) {
        double cs = 0.0;
        for (int r = 0; r < ROWS; ++r) cs += pb[r][tid];
        op_run += cs;
      }
    }
    cur = nxt;
  }

  if (tid < ROWS) {
    lpp[q * BTOT + base_b + tid] = lp_run;
    enp[q * BTOT + base_b + tid] = en_run;
  }
  if (tid < NOPS) atomicAdd(&gacc[tid], op_run);
  if (tid < NMAGS) atomicAdd(&gacc[NOPS + tid], mag_run);
}

// ---- finish: q-ordered partial sums + prob means --------------------------
__global__ void ctrl_fin(const double* __restrict__ ws,
                         float* __restrict__ out) {
  int gid = blockIdx.x * blockDim.x + threadIdx.x;
  if (gid < BTOT) {
    const double* lpp = ws + LPP_D;
    const double* enp = ws + ENP_D;
    double s1 = 0.0, s2 = 0.0;
#pragma unroll
    for (int qq = 0; qq < QC; ++qq) {
      s1 += lpp[qq * BTOT + gid];
      s2 += enp[qq * BTOT + gid];
    }
    out[OUT_LPS + gid] = (float)s1;
    out[OUT_ENTS + gid] = (float)s2;
  } else if (gid < BTOT + NOPS + NMAGS) {
    int t = gid - BTOT;
    double v = ws[GACC_D + t] / 163840.0;
    if (t < NOPS) out[OUT_OPM + t] = (float)v;
    else out[OUT_MAGM + (t - NOPS)] = (float)v;
  }
}

extern "C" void kernel_launch(void* const* d_in, const int* in_sizes, int n_in,
                              void* d_out, int out_size, void* d_ws,
                              size_t ws_size, hipStream_t stream) {
  const float* emb   = (const float*)d_in[0];
  const float* W_ih  = (const float*)d_in[1];
  const float* W_hh  = (const float*)d_in[2];
  const float* b_ih  = (const float*)d_in[3];
  const float* b_hh  = (const float*)d_in[4];
  const float* W_op  = (const float*)d_in[5];
  const float* b_op  = (const float*)d_in[6];
  const float* W_mag = (const float*)d_in[7];
  const float* b_mag = (const float*)d_in[8];
  float* out = (float*)d_out;
  double* ws = (double*)d_ws;

  // fold_in(key(42), s) = threefry2x32(key=(0,42), count=(0,s))
  KeyArr keys;
  for (int s = 0; s < TOT; ++s) {
    uint32_t o0, o1;
    tf2x32(0u, 42u, 0u, (uint32_t)s, o0, o1);
    keys.k[2 * s] = o0;
    keys.k[2 * s + 1] = o1;
  }

  ctrl_prep<<<dim3((HID * NCOL + 25 * NCOL + 255) / 256), dim3(256), 0,
              stream>>>(emb, W_ih, W_hh, ws);
  ctrl_main<<<dim3(NBLK), dim3(NT), 0, stream>>>(
      b_ih, b_hh, W_op, b_op, W_mag, b_mag, ws, ws + GACC_D, ws + LPP_D,
      ws + ENP_D, out, keys);
  ctrl_fin<<<dim3((BTOT + NOPS + NMAGS + 255) / 256), dim3(256), 0, stream>>>(
      ws, out);
}

// Round 11
// 1450.557 us; speedup vs baseline: 1.1723x; 1.1723x over previous
//
#include <hip/hip_runtime.h>
#include <stdint.h>
#include <stddef.h>

// ---------------------------------------------------------------------------
// Controller (LSTM policy sampler) — round 9 kernel (resubmit; round-10 slot
// hit an infra failure, never benched).
// R8 post-mortem: launch_bounds min-wave pressure -> VGPR squeeze -> 1.15 GB
// scratch traffic. R9: NO min-wave bound (compiler-free regalloc, no spill),
// WHH stored f32 (exact upcast in-loop) halving L2 traffic (29->14.5 GB),
// exp64 degree-11, merged c2 division. RPT=4, ROWS=16, 448 thr, 2560 blocks.
// ---------------------------------------------------------------------------

#define NOPS 14
#define NMAGS 10
#define QC 5
#define NSTEP 8
#define TOT 40
#define EMB 32
#define HID 100
#define BTOT 8192
#define ROWS 16
#define RPT 4
#define NT 448
#define NCOL 112
#define NBLK (QC * (BTOT / ROWS))          // 2560
#define HPAD 18

// ws layout (byte offsets; ws is raw)
#define WHHF_B  0                          // float4[HID*NCOL]  = 179200 B
#define PX_B    179200                     // double[25*NCOL*4] =  89600 B
#define LPP_B   268800                     // double[QC*BTOT]   = 327680 B
#define ENP_B   596480                     // double[QC*BTOT]   = 327680 B
#define GACC_B  924160                     // double[24]

// d_out layout (f32)
#define OUT_OPM  (BTOT * TOT)              // 327680
#define OUT_MAGM (OUT_OPM + NOPS)          // 327694
#define OUT_LPS  (OUT_MAGM + NMAGS)        // 327704
#define OUT_ENTS (OUT_LPS + BTOT)          // 335896

struct KeyArr { uint32_t k[TOT * 2]; };

// ---- threefry2x32-20 (jax._src.prng) --------------------------------------
__host__ __device__ inline void tf2x32(uint32_t k0, uint32_t k1,
                                       uint32_t x0, uint32_t x1,
                                       uint32_t& o0, uint32_t& o1) {
  uint32_t k2 = k0 ^ k1 ^ 0x1BD11BDAu;
#define TFR(r) { x0 += x1; x1 = (x1 << (r)) | (x1 >> (32 - (r))); x1 ^= x0; }
  x0 += k0; x1 += k1;
  TFR(13) TFR(15) TFR(26) TFR(6)
  x0 += k1; x1 += k2 + 1u;
  TFR(17) TFR(29) TFR(16) TFR(24)
  x0 += k2; x1 += k0 + 2u;
  TFR(13) TFR(15) TFR(26) TFR(6)
  x0 += k0; x1 += k1 + 3u;
  TFR(17) TFR(29) TFR(16) TFR(24)
  x0 += k1; x1 += k2 + 4u;
  TFR(13) TFR(15) TFR(26) TFR(6)
  x0 += k2; x1 += k0 + 5u;
#undef TFR
  o0 = x0; o1 = x1;
}

// ---- fast f64 exp, degree-11 Taylor on r in [-ln2/2, ln2/2] ---------------
// rel err ~6e-15; needed <=1e-12 (action margins ~1e-6).
__device__ __forceinline__ double exp64(double x) {
  double t = x * 1.4426950408889634074;
  double n = rint(t);
  double r = fma(-n, 6.93147180369123816490e-01, x);
  r = fma(-n, 1.90821492927058770002e-10, r);
  double p = 2.5052108385441720e-8;         // 1/11!
  p = fma(p, r, 2.7557319223985888e-7);
  p = fma(p, r, 2.7557319223985893e-6);
  p = fma(p, r, 2.4801587301587302e-5);
  p = fma(p, r, 1.9841269841269841e-4);
  p = fma(p, r, 1.3888888888888889e-3);
  p = fma(p, r, 8.3333333333333332e-3);
  p = fma(p, r, 4.1666666666666664e-2);
  p = fma(p, r, 1.6666666666666666e-1);
  p = fma(p, r, 0.5);
  p = fma(p, r, 1.0);
  p = fma(p, r, 1.0);
  long long ni = (long long)n;
  double sc = __longlong_as_double((1023LL + ni) << 52);
  return p * sc;
}

// ---- fast f64 log (normal x > 0; abs err ~1e-15) --------------------------
__device__ __forceinline__ double log64(double x) {
  long long b = __double_as_longlong(x);
  long long e = ((b >> 52) & 0x7FF) - 1023;
  double m = __longlong_as_double((b & 0x000FFFFFFFFFFFFFLL) |
                                  0x3FF0000000000000LL);
  if (m > 1.4142135623730951) { m *= 0.5; e += 1; }
  double z = (m - 1.0) / (m + 1.0);
  double z2 = z * z;
  double s = 1.0 / 21.0;
  s = fma(s, z2, 1.0 / 19.0);
  s = fma(s, z2, 1.0 / 17.0);
  s = fma(s, z2, 1.0 / 15.0);
  s = fma(s, z2, 1.0 / 13.0);
  s = fma(s, z2, 1.0 / 11.0);
  s = fma(s, z2, 1.0 / 9.0);
  s = fma(s, z2, 1.0 / 7.0);
  s = fma(s, z2, 1.0 / 5.0);
  s = fma(s, z2, 1.0 / 3.0);
  s = fma(s, z2, 1.0);
  double lm = 2.0 * z * s;
  return fma((double)e, 0.6931471805599453094, lm);
}

__device__ __forceinline__ double tanh64(double x) {
  double t = exp64(2.0 * x);
  return 1.0 - 2.0 / (t + 1.0);
}

// ---- gumbel: partitionable threefry bits -> exact f32 uniform -> f64 ------
__device__ __forceinline__ double gumbel64(uint32_t k0, uint32_t k1,
                                           uint32_t e) {
  uint32_t o0, o1;
  tf2x32(k0, k1, 0u, e, o0, o1);
  uint32_t bits = o0 ^ o1;
  float uf = __uint_as_float((bits >> 9) | 0x3f800000u) - 1.0f;  // exact
  double u = (double)uf;
  if (u == 0.0) u = 1.1754943508222875e-38;
  return -log64(-log64(u));
}

// ---- prep: WHH quads (f32, exact), PX = emb @ W_ih^T (f64), zero gacc -----
__global__ void ctrl_prep(const float* __restrict__ emb,
                          const float* __restrict__ W_ih,
                          const float* __restrict__ W_hh,
                          char* __restrict__ ws) {
  float4* whh = (float4*)(ws + WHHF_B);
  double* px = (double*)(ws + PX_B);
  double* gacc = (double*)(ws + GACC_B);
  int gid = blockIdx.x * blockDim.x + threadIdx.x;
  if (gid < HID * NCOL) {
    int k = gid / NCOL, j = gid % NCOL;
    float4 v = {0.f, 0.f, 0.f, 0.f};
    if (j < HID) {
      v.x = W_hh[(0 * HID + j) * HID + k];
      v.y = W_hh[(1 * HID + j) * HID + k];
      v.z = W_hh[(2 * HID + j) * HID + k];
      v.w = W_hh[(3 * HID + j) * HID + k];
    }
    whh[gid] = v;
  } else if (gid < HID * NCOL + 25 * NCOL) {
    int t = gid - HID * NCOL;
    int a = t / NCOL, j = t % NCOL;
    double* dst = px + 4 * t;
    double v[4] = {0.0, 0.0, 0.0, 0.0};
    if (j < HID && a < 24) {
#pragma unroll
      for (int g = 0; g < 4; ++g) {
        const float* wr = W_ih + (g * HID + j) * EMB;
        const float* ev = emb + a * EMB;
        double acc = 0.0;
        for (int e = 0; e < EMB; ++e)
          acc = fma((double)wr[e], (double)ev[e], acc);
        v[g] = acc;
      }
    }
    dst[0] = v[0]; dst[1] = v[1]; dst[2] = v[2]; dst[3] = v[3];
  }
  if (gid < NOPS + NMAGS) gacc[gid] = 0.0;
}

// ---- head matvec + z + gumbel ---------------------------------------------
template <int K>
__device__ __forceinline__ void head_phase(
    int tid, int base_b, const float* __restrict__ Wh,
    const float* __restrict__ bh, uint32_t key0, uint32_t key1,
    const double (*hb)[HPAD], double (*zb)[16], double (*gb)[16]) {
  if (tid < ROWS * K) {
    int r = tid / K, c = tid - r * K;
    const float* wrow = Wh + c * HID;
    double acc = 0.0;
#pragma unroll 4
    for (int k = 0; k < HID; ++k)
      acc = fma((double)wrow[k], hb[k][r], acc);
    zb[r][c] = 2.5 * tanh64(acc + (double)bh[c]);
    gb[r][c] = gumbel64(key0, key1, (uint32_t)((base_b + r) * K + c));
  }
}

// ---- per-row softmax / entropy / gumbel-argmax ----------------------------
template <int K>
__device__ __forceinline__ void sample_phase(
    int r, int base_b, int sidx, int eoff, double (*zb)[16], double (*gb)[16],
    double (*pb)[16], int* act, float* __restrict__ out, double& lp_run,
    double& en_run) {
  double m = zb[r][0];
#pragma unroll
  for (int k = 1; k < K; ++k) m = fmax(m, zb[r][k]);
  double s = 0.0;
#pragma unroll
  for (int k = 0; k < K; ++k) s += exp64(zb[r][k] - m);
  double ls = log64(s);
  double ent = 0.0, best = 0.0, sel = 0.0;
  int bi = 0;
#pragma unroll
  for (int k = 0; k < K; ++k) {
    double zk = zb[r][k];
    double lp = zk - m - ls;
    double pr = exp64(lp);
    pb[r][k] = pr;
    ent = fma(lp, pr, ent);
    double sc = gb[r][k] + zk;           // argmax(z + gumbel), first-max tie
    if (k == 0 || sc > best) { best = sc; bi = k; sel = lp; }
  }
  out[(size_t)(base_b + r) * TOT + sidx] = (float)bi;
  lp_run += sel;
  en_run += -ent;
  act[r] = bi + eoff;
}

// ---- main -----------------------------------------------------------------
__global__ __launch_bounds__(NT)   // NO min-wave pressure: avoid spills
void ctrl_main(const float* __restrict__ b_ih, const float* __restrict__ b_hh,
               const float* __restrict__ W_op, const float* __restrict__ b_op,
               const float* __restrict__ W_mag, const float* __restrict__ b_mag,
               const char* __restrict__ ws, double* __restrict__ gacc,
               double* __restrict__ lpp, double* __restrict__ enp,
               float* __restrict__ out, KeyArr keys) {
  __shared__ double hbuf[2][HID][HPAD];       // double-buffered h, padded
  __shared__ double zb[ROWS][16], gb[ROWS][16], pb[ROWS][16];
  __shared__ int act[ROWS];

  const int tid = threadIdx.x;
  const int jq = tid % NCOL;
  const int rb = (tid / NCOL) * RPT;
  const int bid = blockIdx.x;
  const int q = bid >> 9;                     // 5 q x 512 row-groups
  const int base_b = (bid & 511) * ROWS;
  const bool on = (jq < HID);

  for (int t = tid; t < 2 * HID * HPAD; t += NT) (&hbuf[0][0][0])[t] = 0.0;
  if (tid < ROWS) act[tid] = 24;              // step-0 input: zero vector

  const float4* WHH = (const float4*)(ws + WHHF_B);
  const double* PX = (const double*)(ws + PX_B);

  double bsi = 0, bsf = 0, bsg = 0, bso = 0;
  if (on) {
    bsi = (double)b_ih[jq]       + (double)b_hh[jq];
    bsf = (double)b_ih[100 + jq] + (double)b_hh[100 + jq];
    bsg = (double)b_ih[200 + jq] + (double)b_hh[200 + jq];
    bso = (double)b_ih[300 + jq] + (double)b_hh[300 + jq];
  }

  double creg[RPT];
#pragma unroll
  for (int r = 0; r < RPT; ++r) creg[r] = 0.0;
  double lp_run = 0.0, en_run = 0.0, op_run = 0.0, mag_run = 0.0;
  int cur = 0;
  __syncthreads();

  for (int js = 0; js < NSTEP; ++js) {
    const int nxt = cur ^ 1;
    // ---- gates = PX[act] + h @ WHH (4 rows/thread, f64 fma, f32 weights) --
    double ai[RPT], af[RPT], ag[RPT], ao[RPT];
#pragma unroll
    for (int r = 0; r < RPT; ++r) {
      const double* px = PX + 4 * ((size_t)act[rb + r] * NCOL + jq);
      ai[r] = px[0]; af[r] = px[1]; ag[r] = px[2]; ao[r] = px[3];
    }
#pragma unroll 2
    for (int k = 0; k < HID; ++k) {
      float4 w = WHH[k * NCOL + jq];
      double wi = (double)w.x, wf = (double)w.y;
      double wg = (double)w.z, wo = (double)w.w;
      const double* hrow = &hbuf[cur][k][rb];
      double2 h01 = *(const double2*)(hrow + 0);
      double2 h23 = *(const double2*)(hrow + 2);
      double hv[RPT] = {h01.x, h01.y, h23.x, h23.y};
#pragma unroll
      for (int r = 0; r < RPT; ++r) {
        ai[r] = fma(wi, hv[r], ai[r]);
        af[r] = fma(wf, hv[r], af[r]);
        ag[r] = fma(wg, hv[r], ag[r]);
        ao[r] = fma(wo, hv[r], ao[r]);
      }
    }
    if (on) {
      double hw[RPT];
#pragma unroll
      for (int r = 0; r < RPT; ++r) {
        double gi = ai[r] + bsi, gf = af[r] + bsf;
        double gg = ag[r] + bsg, go = ao[r] + bso;
        double ef = exp64(-gf);
        double ei = exp64(-gi);
        double eg = exp64(2.0 * gg);
        double eo = exp64(-go);
        // c2 = creg/(1+ef) + (eg-1)/((eg+1)(1+ei)), merged to one divide
        double bdi = 1.0 + ef;
        double ddi = (eg + 1.0) * (1.0 + ei);
        double c2 = fma(creg[r], ddi, (eg - 1.0) * bdi) / (bdi * ddi);
        creg[r] = c2;
        double ec = exp64(2.0 * c2);
        hw[r] = (ec - 1.0) / ((ec + 1.0) * (1.0 + eo));  // sig(o)*tanh(c2)
      }
      double* dst = &hbuf[nxt][jq][rb];
      ((double2*)dst)[0] = make_double2(hw[0], hw[1]);
      ((double2*)dst)[1] = make_double2(hw[2], hw[3]);
    }
    __syncthreads();                         // bar1: h visible, reads done

    const int sidx = q * NSTEP + js;
    const uint32_t key0 = keys.k[2 * sidx], key1 = keys.k[2 * sidx + 1];
    if (js & 1)
      head_phase<NMAGS>(tid, base_b, W_mag, b_mag, key0, key1, hbuf[nxt], zb, gb);
    else
      head_phase<NOPS>(tid, base_b, W_op, b_op, key0, key1, hbuf[nxt], zb, gb);
    __syncthreads();                         // bar2: zb/gb visible

    if (tid < ROWS) {
      if (js & 1)
        sample_phase<NMAGS>(tid, base_b, sidx, NOPS, zb, gb, pb, act, out,
                            lp_run, en_run);
      else
        sample_phase<NOPS>(tid, base_b, sidx, 0, zb, gb, pb, act, out,
                           lp_run, en_run);
    }
    __syncthreads();                         // bar3: pb/act visible

    if (js & 1) {
      if (tid < NMAGS) {
        double cs = 0.0;
        for (int r = 0; r < ROWS; ++r) cs += pb[r][tid];
        mag_run += cs;
      }
    } else {
      if (tid < NOPS) {
        double cs = 0.0;
        for (int r = 0; r < ROWS; ++r) cs += pb[r][tid];
        op_run += cs;
      }
    }
    cur = nxt;
  }

  if (tid < ROWS) {
    lpp[q * BTOT + base_b + tid] = lp_run;
    enp[q * BTOT + base_b + tid] = en_run;
  }
  if (tid < NOPS) atomicAdd(&gacc[tid], op_run);
  if (tid < NMAGS) atomicAdd(&gacc[NOPS + tid], mag_run);
}

// ---- finish: q-ordered partial sums + prob means --------------------------
__global__ void ctrl_fin(const char* __restrict__ ws,
                         float* __restrict__ out) {
  const double* lpp = (const double*)(ws + LPP_B);
  const double* enp = (const double*)(ws + ENP_B);
  const double* gacc = (const double*)(ws + GACC_B);
  int gid = blockIdx.x * blockDim.x + threadIdx.x;
  if (gid < BTOT) {
    double s1 = 0.0, s2 = 0.0;
#pragma unroll
    for (int qq = 0; qq < QC; ++qq) {
      s1 += lpp[qq * BTOT + gid];
      s2 += enp[qq * BTOT + gid];
    }
    out[OUT_LPS + gid] = (float)s1;
    out[OUT_ENTS + gid] = (float)s2;
  } else if (gid < BTOT + NOPS + NMAGS) {
    int t = gid - BTOT;
    double v = gacc[t] / 163840.0;
    if (t < NOPS) out[OUT_OPM + t] = (float)v;
    else out[OUT_MAGM + (t - NOPS)] = (float)v;
  }
}

extern "C" void kernel_launch(void* const* d_in, const int* in_sizes, int n_in,
                              void* d_out, int out_size, void* d_ws,
                              size_t ws_size, hipStream_t stream) {
  const float* emb   = (const float*)d_in[0];
  const float* W_ih  = (const float*)d_in[1];
  const float* W_hh  = (const float*)d_in[2];
  const float* b_ih  = (const float*)d_in[3];
  const float* b_hh  = (const float*)d_in[4];
  const float* W_op  = (const float*)d_in[5];
  const float* b_op  = (const float*)d_in[6];
  const float* W_mag = (const float*)d_in[7];
  const float* b_mag = (const float*)d_in[8];
  float* out = (float*)d_out;
  char* ws = (char*)d_ws;

  // fold_in(key(42), s) = threefry2x32(key=(0,42), count=(0,s))
  KeyArr keys;
  for (int s = 0; s < TOT; ++s) {
    uint32_t o0, o1;
    tf2x32(0u, 42u, 0u, (uint32_t)s, o0, o1);
    keys.k[2 * s] = o0;
    keys.k[2 * s + 1] = o1;
  }

  ctrl_prep<<<dim3((HID * NCOL + 25 * NCOL + 255) / 256), dim3(256), 0,
              stream>>>(emb, W_ih, W_hh, ws);
  ctrl_main<<<dim3(NBLK), dim3(NT), 0, stream>>>(
      b_ih, b_hh, W_op, b_op, W_mag, b_mag, ws,
      (double*)(ws + GACC_B), (double*)(ws + LPP_B), (double*)(ws + ENP_B),
      out, keys);
  ctrl_fin<<<dim3((BTOT + NOPS + NMAGS + 255) / 256), dim3(256), 0, stream>>>(
      ws, out);
}